// Round 1
// baseline (2932.388 us; speedup 1.0000x reference)
//
#include <hip/hip_runtime.h>
#include <hip/hip_bf16.h>
#include <math.h>

#define DIMC 256
#define INNERC 128
#define HEADSC 4
#define DHC 32

__device__ __forceinline__ float gelu_exact(float x) {
    return 0.5f * x * (1.0f + erff(x * 0.70710678118654752f));
}

// ---------------- LayerNorm: one block per row of 256 ----------------
__global__ __launch_bounds__(256)
void ln_kernel(const float* __restrict__ x, const float* __restrict__ g,
               const float* __restrict__ b, float* __restrict__ out)
{
    int i = blockIdx.x;
    int t = threadIdx.x;
    float v = x[(size_t)i * DIMC + t];
    __shared__ float red[4];
    float s = v;
#pragma unroll
    for (int off = 32; off; off >>= 1) s += __shfl_xor(s, off);
    if ((t & 63) == 0) red[t >> 6] = s;
    __syncthreads();
    float mean = (red[0] + red[1] + red[2] + red[3]) * (1.f / DIMC);
    float c = v - mean;
    float s2 = c * c;
#pragma unroll
    for (int off = 32; off; off >>= 1) s2 += __shfl_xor(s2, off);
    __syncthreads();
    if ((t & 63) == 0) red[t >> 6] = s2;
    __syncthreads();
    float var = (red[0] + red[1] + red[2] + red[3]) * (1.f / DIMC);
    out[(size_t)i * DIMC + t] = c * rsqrtf(var + 1e-5f) * g[t] + b[t];
}

// ---------------- GEMM: C[M][OUT] = A[M][K] @ W[OUT][K]^T + bias ----------------
// EPI: 0 = none, 1 = gelu, 2 = += res
// 64x64 tile, BK=32, 256 threads, 4x4 per thread, XOR-swizzled LDS (float4).
template<int EPI>
__global__ __launch_bounds__(256)
void gemm_kernel(const float* __restrict__ A, const float* __restrict__ W,
                 const float* __restrict__ bias, const float* __restrict__ res,
                 float* __restrict__ C, int M, int K, int OUT)
{
    __shared__ float As[64][32];
    __shared__ float Ws[64][32];
    int tid = threadIdx.x;
    int bm = blockIdx.x * 64, bn = blockIdx.y * 64;
    int tr = tid >> 4, tc = tid & 15;
    float acc[4][4] = {};
    for (int k0 = 0; k0 < K; k0 += 32) {
#pragma unroll
        for (int i2 = 0; i2 < 2; ++i2) {
            int idx = tid * 2 + i2;           // 0..511
            int r = idx >> 3, c4 = idx & 7;   // row, float4-column
            int sw = (c4 ^ ((r >> 2) & 7)) * 4;
            int gr = bm + r;
            float4 vA = make_float4(0.f, 0.f, 0.f, 0.f);
            if (gr < M) vA = *(const float4*)&A[(size_t)gr * K + k0 + c4 * 4];
            *(float4*)&As[r][sw] = vA;
            float4 vW = *(const float4*)&W[(size_t)(bn + r) * K + k0 + c4 * 4];
            *(float4*)&Ws[r][sw] = vW;
        }
        __syncthreads();
#pragma unroll
        for (int kk4 = 0; kk4 < 8; ++kk4) {
            float4 a[4], b[4];
#pragma unroll
            for (int i = 0; i < 4; ++i) {
                int r = tr * 4 + i;
                a[i] = *(float4*)&As[r][((kk4 ^ ((r >> 2) & 7))) * 4];
            }
#pragma unroll
            for (int j = 0; j < 4; ++j) {
                int r = tc * 4 + j;
                b[j] = *(float4*)&Ws[r][((kk4 ^ ((r >> 2) & 7))) * 4];
            }
#pragma unroll
            for (int i = 0; i < 4; ++i)
#pragma unroll
                for (int j = 0; j < 4; ++j)
                    acc[i][j] += a[i].x * b[j].x + a[i].y * b[j].y
                               + a[i].z * b[j].z + a[i].w * b[j].w;
        }
        __syncthreads();
    }
#pragma unroll
    for (int i = 0; i < 4; ++i) {
        int gr = bm + tr * 4 + i;
        if (gr >= M) continue;
#pragma unroll
        for (int j = 0; j < 4; ++j) {
            int gc = bn + tc * 4 + j;
            float val = acc[i][j] + bias[gc];
            if (EPI == 1) val = gelu_exact(val);
            if (EPI == 2) val += res[(size_t)gr * OUT + gc];
            C[(size_t)gr * OUT + gc] = val;
        }
    }
}

// ---------------- CSR build ----------------
__global__ void count_kernel(const int* __restrict__ dst, int* __restrict__ count, int E)
{
    int e = blockIdx.x * blockDim.x + threadIdx.x;
    if (e < E) atomicAdd(&count[dst[e]], 1);
}

__global__ __launch_bounds__(1024)
void scan_kernel(const int* __restrict__ count, int* __restrict__ rowptr, int N)
{
    __shared__ int sdata[1024];
    __shared__ int carry_s;
    int t = threadIdx.x;
    if (t == 0) { carry_s = 0; rowptr[0] = 0; }
    __syncthreads();
    for (int base = 0; base < N; base += 1024) {
        int idx = base + t;
        int v = (idx < N) ? count[idx] : 0;
        sdata[t] = v;
        __syncthreads();
        for (int off = 1; off < 1024; off <<= 1) {
            int add = (t >= off) ? sdata[t - off] : 0;
            __syncthreads();
            sdata[t] += add;
            __syncthreads();
        }
        if (idx < N) rowptr[idx + 1] = carry_s + sdata[t];
        __syncthreads();
        if (t == 0) carry_s += sdata[1023];
        __syncthreads();
    }
}

__global__ void scatter_kernel(const int* __restrict__ src, const int* __restrict__ dst,
                               const int* __restrict__ rowptr, int* __restrict__ cursor,
                               int* __restrict__ srcperm, int E)
{
    int e = blockIdx.x * blockDim.x + threadIdx.x;
    if (e < E) {
        int d = dst[e];
        int pos = rowptr[d] + atomicAdd(&cursor[d], 1);
        srcperm[pos] = src[e];
    }
}

// ---------------- Attention: one block (128 thr) per destination node ----------------
// thread t: head h = t>>5, dim d = t&31. Two passes over incoming edges (CSR).
__global__ __launch_bounds__(128)
void attn_kernel(const float* __restrict__ q, const float* __restrict__ k,
                 const float* __restrict__ v, const int* __restrict__ rowptr,
                 const int* __restrict__ srcperm, float* __restrict__ alphabuf,
                 float* __restrict__ agg)
{
    int i = blockIdx.x;
    int t = threadIdx.x;
    int h = t >> 5, d = t & 31;
    int beg = rowptr[i], end = rowptr[i + 1];
    float qv = q[(size_t)i * INNERC + t];
    float m = -3.4e38f;
    const float scale = 0.17677669529663687f; // 1/sqrt(32)
    for (int p = beg; p < end; ++p) {
        int j = srcperm[p];
        float prod = qv * k[(size_t)j * INNERC + h * DHC + d];
#pragma unroll
        for (int off = 16; off; off >>= 1) prod += __shfl_xor(prod, off, 32);
        float a = prod * scale;
        if (d == 0) alphabuf[(size_t)p * HEADSC + h] = a;
        m = fmaxf(m, a);
    }
    float denom = 0.f, acc = 0.f;
    for (int p = beg; p < end; ++p) {
        int j = srcperm[p];
        float a = alphabuf[(size_t)p * HEADSC + h];
        float ex = expf(a - m);
        denom += ex;
        acc += ex * v[(size_t)j * INNERC + h * DHC + d];
    }
    agg[(size_t)i * INNERC + t] = acc / (denom + 1e-16f);
}

// ---------------- Launch ----------------
extern "C" void kernel_launch(void* const* d_in, const int* in_sizes, int n_in,
                              void* d_out, int out_size, void* d_ws, size_t ws_size,
                              hipStream_t stream)
{
    const float* x    = (const float*)d_in[0];
    const int*   ei   = (const int*)  d_in[1];
    const float* ln1g = (const float*)d_in[2];
    const float* ln1b = (const float*)d_in[3];
    const float* wq   = (const float*)d_in[4];
    const float* bq   = (const float*)d_in[5];
    const float* wk   = (const float*)d_in[6];
    const float* bk   = (const float*)d_in[7];
    const float* wv   = (const float*)d_in[8];
    const float* bv   = (const float*)d_in[9];
    const float* wo   = (const float*)d_in[10];
    const float* bo   = (const float*)d_in[11];
    const float* ln2g = (const float*)d_in[12];
    const float* ln2b = (const float*)d_in[13];
    const float* w1   = (const float*)d_in[14];
    const float* b1   = (const float*)d_in[15];
    const float* w2   = (const float*)d_in[16];
    const float* b2   = (const float*)d_in[17];

    const int N = in_sizes[0] / DIMC;   // 20000
    const int E = in_sizes[1] / 2;      // 320000
    const int* srcIdx = ei;
    const int* dstIdx = ei + E;

    char* p = (char*)d_ws;
    auto alloc = [&](size_t bytes) {
        char* r = p;
        p += (bytes + 255) & ~(size_t)255;
        return r;
    };
    float* xbuf     = (float*)alloc((size_t)N * DIMC * 4);
    float* h        = (float*)alloc((size_t)N * DIMC * 4);
    float* q        = (float*)alloc((size_t)N * INNERC * 4);
    float* k        = (float*)alloc((size_t)N * INNERC * 4);
    float* v        = (float*)alloc((size_t)N * INNERC * 4);
    float* agg      = (float*)alloc((size_t)N * INNERC * 4);
    float* u        = (float*)alloc((size_t)N * 1024 * 4);
    float* alphabuf = (float*)alloc((size_t)E * HEADSC * 4);
    int*   rowptr   = (int*)alloc((size_t)(N + 1) * 4);
    int*   cnt      = (int*)alloc((size_t)N * 4);
    int*   srcperm  = (int*)alloc((size_t)E * 4);

    // CSR build (recomputed every call; deterministic work)
    hipMemsetAsync(cnt, 0, (size_t)N * 4, stream);
    count_kernel<<<(E + 255) / 256, 256, 0, stream>>>(dstIdx, cnt, E);
    scan_kernel<<<1, 1024, 0, stream>>>(cnt, rowptr, N);
    hipMemsetAsync(cnt, 0, (size_t)N * 4, stream);
    scatter_kernel<<<(E + 255) / 256, 256, 0, stream>>>(srcIdx, dstIdx, rowptr, cnt, srcperm, E);

    int mtiles = (N + 63) / 64;
    for (int l = 0; l < 4; ++l) {
        const float* xin = (l == 0) ? x : xbuf;
        ln_kernel<<<N, 256, 0, stream>>>(xin, ln1g + l * DIMC, ln1b + l * DIMC, h);
        gemm_kernel<0><<<dim3(mtiles, INNERC / 64), 256, 0, stream>>>(
            h, wq + (size_t)l * INNERC * DIMC, bq + l * INNERC, nullptr, q, N, DIMC, INNERC);
        gemm_kernel<0><<<dim3(mtiles, INNERC / 64), 256, 0, stream>>>(
            h, wk + (size_t)l * INNERC * DIMC, bk + l * INNERC, nullptr, k, N, DIMC, INNERC);
        gemm_kernel<0><<<dim3(mtiles, INNERC / 64), 256, 0, stream>>>(
            h, wv + (size_t)l * INNERC * DIMC, bv + l * INNERC, nullptr, v, N, DIMC, INNERC);
        attn_kernel<<<N, 128, 0, stream>>>(q, k, v, rowptr, srcperm, alphabuf, agg);
        gemm_kernel<2><<<dim3(mtiles, DIMC / 64), 256, 0, stream>>>(
            agg, wo + (size_t)l * DIMC * INNERC, bo + l * DIMC, xin, xbuf, N, INNERC, DIMC);
        ln_kernel<<<N, 256, 0, stream>>>(xbuf, ln2g + l * DIMC, ln2b + l * DIMC, h);
        gemm_kernel<1><<<dim3(mtiles, 1024 / 64), 256, 0, stream>>>(
            h, w1 + (size_t)l * 1024 * DIMC, b1 + l * 1024, nullptr, u, N, DIMC, 1024);
        float* xout = (l == 3) ? (float*)d_out : xbuf;
        gemm_kernel<2><<<dim3(mtiles, DIMC / 64), 256, 0, stream>>>(
            u, w2 + (size_t)l * DIMC * 1024, b2 + l * DIMC, xbuf, xout, N, 1024, DIMC);
    }
}

// Round 2
// 930.570 us; speedup vs baseline: 3.1512x; 3.1512x over previous
//
#include <hip/hip_runtime.h>
#include <hip/hip_bf16.h>
#include <math.h>

#define DIMC 256
#define INNERC 128
#define HEADSC 4
#define DHC 32
#define QKVC 384

typedef __attribute__((ext_vector_type(8))) short bf16frag;   // 8 bf16 = 4 VGPRs
typedef __attribute__((ext_vector_type(4))) float f32x4;

__device__ __forceinline__ float gelu_exact(float x) {
    return 0.5f * x * (1.0f + erff(x * 0.70710678118654752f));
}

__device__ __forceinline__ void gload_lds16(const void* g, void* l) {
    __builtin_amdgcn_global_load_lds(
        (const __attribute__((address_space(1))) void*)g,
        (__attribute__((address_space(3))) void*)l, 16, 0, 0);
}

// ---------------- LayerNorm: fp32 in, bf16 out ----------------
__global__ __launch_bounds__(256)
void ln_kernel(const float* __restrict__ x, const float* __restrict__ g,
               const float* __restrict__ b, __hip_bfloat16* __restrict__ out)
{
    int i = blockIdx.x;
    int t = threadIdx.x;
    float v = x[(size_t)i * DIMC + t];
    __shared__ float red[4];
    float s = v;
#pragma unroll
    for (int off = 32; off; off >>= 1) s += __shfl_xor(s, off);
    if ((t & 63) == 0) red[t >> 6] = s;
    __syncthreads();
    float mean = (red[0] + red[1] + red[2] + red[3]) * (1.f / DIMC);
    float c = v - mean;
    float s2 = c * c;
#pragma unroll
    for (int off = 32; off; off >>= 1) s2 += __shfl_xor(s2, off);
    __syncthreads();
    if ((t & 63) == 0) red[t >> 6] = s2;
    __syncthreads();
    float var = (red[0] + red[1] + red[2] + red[3]) * (1.f / DIMC);
    out[(size_t)i * DIMC + t] =
        __float2bfloat16(c * rsqrtf(var + 1e-5f) * g[t] + b[t]);
}

// ---------------- fp32 -> bf16 convert (n % 4 == 0) ----------------
__global__ void f2b_kernel(const float* __restrict__ src,
                           __hip_bfloat16* __restrict__ dst, int n)
{
    int i = (blockIdx.x * blockDim.x + threadIdx.x) * 4;
    if (i < n) {
        float4 v = *(const float4*)(src + i);
        dst[i + 0] = __float2bfloat16(v.x);
        dst[i + 1] = __float2bfloat16(v.y);
        dst[i + 2] = __float2bfloat16(v.z);
        dst[i + 3] = __float2bfloat16(v.w);
    }
}

// ---------------- pack wq/wk/wv -> wqkv bf16 [4][384][256], biases [4][384] ----
__global__ __launch_bounds__(256)
void packqkv_kernel(const float* __restrict__ wq, const float* __restrict__ wk,
                    const float* __restrict__ wv, const float* __restrict__ bq,
                    const float* __restrict__ bk, const float* __restrict__ bv,
                    __hip_bfloat16* __restrict__ wqkv, float* __restrict__ bqkv)
{
    int row = blockIdx.x;                 // 0 .. 4*384-1
    int l = row / QKVC, c = row % QKVC;
    int which = c >> 7, cc = c & 127;
    const float* srcw = which == 0 ? wq : which == 1 ? wk : wv;
    const float* srcb = which == 0 ? bq : which == 1 ? bk : bv;
    srcw += ((size_t)l * INNERC + cc) * DIMC;
    wqkv[(size_t)row * DIMC + threadIdx.x] = __float2bfloat16(srcw[threadIdx.x]);
    if (threadIdx.x == 0) bqkv[row] = srcb[l * INNERC + cc];
}

// ---------------- MFMA GEMM: C[M][OUT] = A[M][K] @ W[OUT][K]^T + bias --------
// A, W bf16 row-major (K contiguous). 128x128 tile, BK=64, 256 thr (2x2 waves),
// 4x4 16x16x32 fragments per wave. global_load_lds(16B) staging with
// pre-swizzled global source; XOR-swizzled ds_read_b128 fragment loads.
// EPI: 0 = bias -> bf16 out; 1 = bias+gelu -> bf16 out; 2 = bias+res -> fp32 out.
template<int EPI>
__global__ __launch_bounds__(256)
void mfma_gemm(const __hip_bfloat16* __restrict__ A,
               const __hip_bfloat16* __restrict__ W,
               const float* __restrict__ bias, const float* __restrict__ res,
               void* __restrict__ Cout, int M, int K, int OUT)
{
    __shared__ char lds[128 * 64 * 2 * 2];          // A tile 16KB + B tile 16KB
    char* As = lds;
    char* Ws = lds + 128 * 64 * 2;
    int tid = threadIdx.x;
    int lane = tid & 63;
    int w = tid >> 6;
    int wr = w >> 1, wc = w & 1;
    int bm = blockIdx.x * 128, bn = blockIdx.y * 128;

    f32x4 acc[4][4] = {};

    for (int k0 = 0; k0 < K; k0 += 64) {
        // ---- stage: 1024 16B chunks each for A and B; 256 thr x 4 iters ----
#pragma unroll
        for (int it = 0; it < 4; ++it) {
            int chunk = it * 256 + tid;
            int r = chunk >> 3;                      // tile row 0..127
            int sc = (chunk & 7) ^ (r & 7);          // inverse-swizzled src chunk
            int grow = bm + r;
            if (grow < M)                            // wave-uniform (M%8==0)
                gload_lds16((const char*)A + ((size_t)grow * K + k0) * 2 + sc * 16,
                            As + chunk * 16);
            gload_lds16((const char*)W + ((size_t)(bn + r) * K + k0) * 2 + sc * 16,
                        Ws + chunk * 16);
        }
        __syncthreads();                             // drains vmcnt before use

        // ---- compute: 2 K-slices of 32, 16 MFMA each ----
#pragma unroll
        for (int s = 0; s < 2; ++s) {
            bf16frag af[4], bfr[4];
            int kb = s * 64 + ((lane >> 4) << 4);    // byte offset in row
#pragma unroll
            for (int m = 0; m < 4; ++m) {
                int ar = wr * 64 + m * 16 + (lane & 15);
                af[m] = *(const bf16frag*)(As + ar * 128 + (kb ^ ((ar & 7) << 4)));
            }
#pragma unroll
            for (int n = 0; n < 4; ++n) {
                int br = wc * 64 + n * 16 + (lane & 15);
                bfr[n] = *(const bf16frag*)(Ws + br * 128 + (kb ^ ((br & 7) << 4)));
            }
#pragma unroll
            for (int m = 0; m < 4; ++m)
#pragma unroll
                for (int n = 0; n < 4; ++n)
                    acc[m][n] = __builtin_amdgcn_mfma_f32_16x16x32_bf16(
                        af[m], bfr[n], acc[m][n], 0, 0, 0);
        }
        __syncthreads();
    }

    // ---- epilogue: C/D layout col=lane&15, row=(lane>>4)*4+r ----
#pragma unroll
    for (int m = 0; m < 4; ++m)
#pragma unroll
        for (int r = 0; r < 4; ++r) {
            int grow = bm + wr * 64 + m * 16 + ((lane >> 4) << 2) + r;
            if (grow < M) {
#pragma unroll
                for (int n = 0; n < 4; ++n) {
                    int gcol = bn + wc * 64 + n * 16 + (lane & 15);
                    float val = acc[m][n][r] + bias[gcol];
                    if (EPI == 1) val = gelu_exact(val);
                    if (EPI == 2) {
                        val += res[(size_t)grow * OUT + gcol];
                        ((float*)Cout)[(size_t)grow * OUT + gcol] = val;
                    } else {
                        ((__hip_bfloat16*)Cout)[(size_t)grow * OUT + gcol] =
                            __float2bfloat16(val);
                    }
                }
            }
        }
}

// ---------------- CSR build ----------------
__global__ void count_kernel(const int* __restrict__ dst, int* __restrict__ count, int E)
{
    int e = blockIdx.x * blockDim.x + threadIdx.x;
    if (e < E) atomicAdd(&count[dst[e]], 1);
}

__global__ __launch_bounds__(1024)
void scan_kernel(const int* __restrict__ count, int* __restrict__ rowptr, int N)
{
    __shared__ int sdata[1024];
    __shared__ int carry_s;
    int t = threadIdx.x;
    if (t == 0) { carry_s = 0; rowptr[0] = 0; }
    __syncthreads();
    for (int base = 0; base < N; base += 1024) {
        int idx = base + t;
        int v = (idx < N) ? count[idx] : 0;
        sdata[t] = v;
        __syncthreads();
        for (int off = 1; off < 1024; off <<= 1) {
            int add = (t >= off) ? sdata[t - off] : 0;
            __syncthreads();
            sdata[t] += add;
            __syncthreads();
        }
        if (idx < N) rowptr[idx + 1] = carry_s + sdata[t];
        __syncthreads();
        if (t == 0) carry_s += sdata[1023];
        __syncthreads();
    }
}

__global__ void scatter_kernel(const int* __restrict__ src, const int* __restrict__ dst,
                               const int* __restrict__ rowptr, int* __restrict__ cursor,
                               int* __restrict__ srcperm, int E)
{
    int e = blockIdx.x * blockDim.x + threadIdx.x;
    if (e < E) {
        int d = dst[e];
        int pos = rowptr[d] + atomicAdd(&cursor[d], 1);
        srcperm[pos] = src[e];
    }
}

// ---------------- Attention: one block (128 thr) per destination node -------
// qkv packed bf16 [N][384] (q|k|v). thread t: head h=t>>5, dim d=t&31.
__global__ __launch_bounds__(128)
void attn_kernel(const __hip_bfloat16* __restrict__ qkv, const int* __restrict__ rowptr,
                 const int* __restrict__ srcperm, float* __restrict__ alphabuf,
                 __hip_bfloat16* __restrict__ agg)
{
    int i = blockIdx.x;
    int t = threadIdx.x;
    int h = t >> 5;
    int beg = rowptr[i], end = rowptr[i + 1];
    float qv = __bfloat162float(qkv[(size_t)i * QKVC + t]);
    float m = -3.4e38f;
    const float scale = 0.17677669529663687f; // 1/sqrt(32)
    for (int p = beg; p < end; ++p) {
        int j = srcperm[p];
        float prod = qv * __bfloat162float(qkv[(size_t)j * QKVC + 128 + t]);
#pragma unroll
        for (int off = 16; off; off >>= 1) prod += __shfl_xor(prod, off, 32);
        float a = prod * scale;
        if ((t & 31) == 0) alphabuf[(size_t)p * HEADSC + h] = a;
        m = fmaxf(m, a);
    }
    float denom = 0.f, acc = 0.f;
    for (int p = beg; p < end; ++p) {
        int j = srcperm[p];
        float a = alphabuf[(size_t)p * HEADSC + h];
        float ex = expf(a - m);
        denom += ex;
        acc += ex * __bfloat162float(qkv[(size_t)j * QKVC + 256 + t]);
    }
    agg[(size_t)i * INNERC + t] = __float2bfloat16(acc / (denom + 1e-16f));
}

// ---------------- Launch ----------------
extern "C" void kernel_launch(void* const* d_in, const int* in_sizes, int n_in,
                              void* d_out, int out_size, void* d_ws, size_t ws_size,
                              hipStream_t stream)
{
    const float* x    = (const float*)d_in[0];
    const int*   ei   = (const int*)  d_in[1];
    const float* ln1g = (const float*)d_in[2];
    const float* ln1b = (const float*)d_in[3];
    const float* wq   = (const float*)d_in[4];
    const float* bq   = (const float*)d_in[5];
    const float* wk   = (const float*)d_in[6];
    const float* bk   = (const float*)d_in[7];
    const float* wv   = (const float*)d_in[8];
    const float* bv   = (const float*)d_in[9];
    const float* wo   = (const float*)d_in[10];
    const float* bo   = (const float*)d_in[11];
    const float* ln2g = (const float*)d_in[12];
    const float* ln2b = (const float*)d_in[13];
    const float* w1   = (const float*)d_in[14];
    const float* b1   = (const float*)d_in[15];
    const float* w2   = (const float*)d_in[16];
    const float* b2   = (const float*)d_in[17];

    const int N = in_sizes[0] / DIMC;   // 20000
    const int E = in_sizes[1] / 2;      // 320000
    const int* srcIdx = ei;
    const int* dstIdx = ei + E;

    char* p = (char*)d_ws;
    auto alloc = [&](size_t bytes) {
        char* r = p;
        p += (bytes + 255) & ~(size_t)255;
        return r;
    };
    float*          xbuf   = (float*)alloc((size_t)N * DIMC * 4);
    __hip_bfloat16* h      = (__hip_bfloat16*)alloc((size_t)N * DIMC * 2);
    __hip_bfloat16* qkv    = (__hip_bfloat16*)alloc((size_t)N * QKVC * 2);
    __hip_bfloat16* agg    = (__hip_bfloat16*)alloc((size_t)N * INNERC * 2);
    __hip_bfloat16* u      = (__hip_bfloat16*)alloc((size_t)N * 1024 * 2);
    float*          alphabuf = (float*)alloc((size_t)E * HEADSC * 4);
    int*            rowptr = (int*)alloc((size_t)(N + 1) * 4);
    int*            cnt    = (int*)alloc((size_t)N * 4);
    int*            srcperm= (int*)alloc((size_t)E * 4);
    __hip_bfloat16* wqkvB  = (__hip_bfloat16*)alloc((size_t)4 * QKVC * DIMC * 2);
    float*          bqkvF  = (float*)alloc((size_t)4 * QKVC * 4);
    __hip_bfloat16* woB    = (__hip_bfloat16*)alloc((size_t)4 * DIMC * INNERC * 2);
    __hip_bfloat16* w1B    = (__hip_bfloat16*)alloc((size_t)4 * 1024 * DIMC * 2);
    __hip_bfloat16* w2B    = (__hip_bfloat16*)alloc((size_t)4 * DIMC * 1024 * 2);

    // Weight conversion (per-call, deterministic)
    packqkv_kernel<<<4 * QKVC, 256, 0, stream>>>(wq, wk, wv, bq, bk, bv, wqkvB, bqkvF);
    {
        int n = 4 * DIMC * INNERC;
        f2b_kernel<<<(n / 4 + 255) / 256, 256, 0, stream>>>(wo, woB, n);
        n = 4 * 1024 * DIMC;
        f2b_kernel<<<(n / 4 + 255) / 256, 256, 0, stream>>>(w1, w1B, n);
        f2b_kernel<<<(n / 4 + 255) / 256, 256, 0, stream>>>(w2, w2B, n);
    }

    // CSR build
    hipMemsetAsync(cnt, 0, (size_t)N * 4, stream);
    count_kernel<<<(E + 255) / 256, 256, 0, stream>>>(dstIdx, cnt, E);
    scan_kernel<<<1, 1024, 0, stream>>>(cnt, rowptr, N);
    hipMemsetAsync(cnt, 0, (size_t)N * 4, stream);
    scatter_kernel<<<(E + 255) / 256, 256, 0, stream>>>(srcIdx, dstIdx, rowptr, cnt, srcperm, E);

    int mt = (N + 127) / 128;   // 157
    for (int l = 0; l < 4; ++l) {
        const float* xin = (l == 0) ? x : xbuf;
        ln_kernel<<<N, 256, 0, stream>>>(xin, ln1g + l * DIMC, ln1b + l * DIMC, h);
        mfma_gemm<0><<<dim3(mt, QKVC / 128), 256, 0, stream>>>(
            h, wqkvB + (size_t)l * QKVC * DIMC, bqkvF + l * QKVC, nullptr,
            qkv, N, DIMC, QKVC);
        attn_kernel<<<N, 128, 0, stream>>>(qkv, rowptr, srcperm, alphabuf, agg);
        mfma_gemm<2><<<dim3(mt, DIMC / 128), 256, 0, stream>>>(
            agg, woB + (size_t)l * DIMC * INNERC, bo + l * DIMC, xin,
            xbuf, N, INNERC, DIMC);
        ln_kernel<<<N, 256, 0, stream>>>(xbuf, ln2g + l * DIMC, ln2b + l * DIMC, h);
        mfma_gemm<1><<<dim3(mt, 1024 / 128), 256, 0, stream>>>(
            h, w1B + (size_t)l * 1024 * DIMC, b1 + l * 1024, nullptr,
            u, N, DIMC, 1024);
        float* xout = (l == 3) ? (float*)d_out : xbuf;
        mfma_gemm<2><<<dim3(mt, DIMC / 128), 256, 0, stream>>>(
            u, w2B + (size_t)l * DIMC * 1024, b2 + l * DIMC, xbuf,
            xout, N, 1024, DIMC);
    }
}

// Round 3
// 779.405 us; speedup vs baseline: 3.7623x; 1.1939x over previous
//
#include <hip/hip_runtime.h>
#include <hip/hip_bf16.h>
#include <math.h>

#define DIMC 256
#define INNERC 128
#define HEADSC 4
#define DHC 32
#define QKVC 384

typedef __attribute__((ext_vector_type(8))) short bf16frag;   // 8 bf16 = 4 VGPRs
typedef __attribute__((ext_vector_type(4))) float f32x4;

__device__ __forceinline__ float gelu_exact(float x) {
    return 0.5f * x * (1.0f + erff(x * 0.70710678118654752f));
}

__device__ __forceinline__ float b2f(short s) {
    return __uint_as_float(((unsigned)(unsigned short)s) << 16);
}

__device__ __forceinline__ void gload_lds16(const void* g, void* l) {
    __builtin_amdgcn_global_load_lds(
        (const __attribute__((address_space(1))) void*)g,
        (__attribute__((address_space(3))) void*)l, 16, 0, 0);
}

// ---------------- LayerNorm: fp32 in, bf16 out ----------------
__global__ __launch_bounds__(256)
void ln_kernel(const float* __restrict__ x, const float* __restrict__ g,
               const float* __restrict__ b, __hip_bfloat16* __restrict__ out)
{
    int i = blockIdx.x;
    int t = threadIdx.x;
    float v = x[(size_t)i * DIMC + t];
    __shared__ float red[4];
    float s = v;
#pragma unroll
    for (int off = 32; off; off >>= 1) s += __shfl_xor(s, off);
    if ((t & 63) == 0) red[t >> 6] = s;
    __syncthreads();
    float mean = (red[0] + red[1] + red[2] + red[3]) * (1.f / DIMC);
    float c = v - mean;
    float s2 = c * c;
#pragma unroll
    for (int off = 32; off; off >>= 1) s2 += __shfl_xor(s2, off);
    __syncthreads();
    if ((t & 63) == 0) red[t >> 6] = s2;
    __syncthreads();
    float var = (red[0] + red[1] + red[2] + red[3]) * (1.f / DIMC);
    out[(size_t)i * DIMC + t] =
        __float2bfloat16(c * rsqrtf(var + 1e-5f) * g[t] + b[t]);
}

// ---------------- fp32 -> bf16 convert (n % 4 == 0) ----------------
__global__ void f2b_kernel(const float* __restrict__ src,
                           __hip_bfloat16* __restrict__ dst, int n)
{
    int i = (blockIdx.x * blockDim.x + threadIdx.x) * 4;
    if (i < n) {
        float4 v = *(const float4*)(src + i);
        dst[i + 0] = __float2bfloat16(v.x);
        dst[i + 1] = __float2bfloat16(v.y);
        dst[i + 2] = __float2bfloat16(v.z);
        dst[i + 3] = __float2bfloat16(v.w);
    }
}

// ---------------- pack wq/wk/wv -> wqkv bf16 [4][384][256], biases [4][384] ----
__global__ __launch_bounds__(256)
void packqkv_kernel(const float* __restrict__ wq, const float* __restrict__ wk,
                    const float* __restrict__ wv, const float* __restrict__ bq,
                    const float* __restrict__ bk, const float* __restrict__ bv,
                    __hip_bfloat16* __restrict__ wqkv, float* __restrict__ bqkv)
{
    int row = blockIdx.x;                 // 0 .. 4*384-1
    int l = row / QKVC, c = row % QKVC;
    int which = c >> 7, cc = c & 127;
    const float* srcw = which == 0 ? wq : which == 1 ? wk : wv;
    const float* srcb = which == 0 ? bq : which == 1 ? bk : bv;
    srcw += ((size_t)l * INNERC + cc) * DIMC;
    wqkv[(size_t)row * DIMC + threadIdx.x] = __float2bfloat16(srcw[threadIdx.x]);
    if (threadIdx.x == 0) bqkv[row] = srcb[l * INNERC + cc];
}

// ---------------- MFMA GEMM: C[M][OUT] = A[M][K] @ W[OUT][K]^T + bias --------
template<int EPI>
__global__ __launch_bounds__(256)
void mfma_gemm(const __hip_bfloat16* __restrict__ A,
               const __hip_bfloat16* __restrict__ W,
               const float* __restrict__ bias, const float* __restrict__ res,
               void* __restrict__ Cout, int M, int K, int OUT)
{
    __shared__ char lds[128 * 64 * 2 * 2];          // A tile 16KB + B tile 16KB
    char* As = lds;
    char* Ws = lds + 128 * 64 * 2;
    int tid = threadIdx.x;
    int lane = tid & 63;
    int w = tid >> 6;
    int wr = w >> 1, wc = w & 1;
    int bm = blockIdx.x * 128, bn = blockIdx.y * 128;

    f32x4 acc[4][4] = {};

    for (int k0 = 0; k0 < K; k0 += 64) {
#pragma unroll
        for (int it = 0; it < 4; ++it) {
            int chunk = it * 256 + tid;
            int r = chunk >> 3;                      // tile row 0..127
            int sc = (chunk & 7) ^ (r & 7);          // inverse-swizzled src chunk
            int grow = bm + r;
            if (grow < M)                            // wave-uniform (M%8==0)
                gload_lds16((const char*)A + ((size_t)grow * K + k0) * 2 + sc * 16,
                            As + chunk * 16);
            gload_lds16((const char*)W + ((size_t)(bn + r) * K + k0) * 2 + sc * 16,
                        Ws + chunk * 16);
        }
        __syncthreads();

#pragma unroll
        for (int s = 0; s < 2; ++s) {
            bf16frag af[4], bfr[4];
            int kb = s * 64 + ((lane >> 4) << 4);    // byte offset in row
#pragma unroll
            for (int m = 0; m < 4; ++m) {
                int ar = wr * 64 + m * 16 + (lane & 15);
                af[m] = *(const bf16frag*)(As + ar * 128 + (kb ^ ((ar & 7) << 4)));
            }
#pragma unroll
            for (int n = 0; n < 4; ++n) {
                int br = wc * 64 + n * 16 + (lane & 15);
                bfr[n] = *(const bf16frag*)(Ws + br * 128 + (kb ^ ((br & 7) << 4)));
            }
#pragma unroll
            for (int m = 0; m < 4; ++m)
#pragma unroll
                for (int n = 0; n < 4; ++n)
                    acc[m][n] = __builtin_amdgcn_mfma_f32_16x16x32_bf16(
                        af[m], bfr[n], acc[m][n], 0, 0, 0);
        }
        __syncthreads();
    }

#pragma unroll
    for (int m = 0; m < 4; ++m)
#pragma unroll
        for (int r = 0; r < 4; ++r) {
            int grow = bm + wr * 64 + m * 16 + ((lane >> 4) << 2) + r;
            if (grow < M) {
#pragma unroll
                for (int n = 0; n < 4; ++n) {
                    int gcol = bn + wc * 64 + n * 16 + (lane & 15);
                    float val = acc[m][n][r] + bias[gcol];
                    if (EPI == 1) val = gelu_exact(val);
                    if (EPI == 2) {
                        val += res[(size_t)grow * OUT + gcol];
                        ((float*)Cout)[(size_t)grow * OUT + gcol] = val;
                    } else {
                        ((__hip_bfloat16*)Cout)[(size_t)grow * OUT + gcol] =
                            __float2bfloat16(val);
                    }
                }
            }
        }
}

// ---------------- CSR build ----------------
__global__ void count_kernel(const int* __restrict__ dst, int* __restrict__ count, int E)
{
    int e = blockIdx.x * blockDim.x + threadIdx.x;
    if (e < E) atomicAdd(&count[dst[e]], 1);
}

__global__ __launch_bounds__(1024)
void scan_kernel(const int* __restrict__ count, int* __restrict__ rowptr, int N)
{
    __shared__ int sdata[1024];
    __shared__ int carry_s;
    int t = threadIdx.x;
    if (t == 0) { carry_s = 0; rowptr[0] = 0; }
    __syncthreads();
    for (int base = 0; base < N; base += 1024) {
        int idx = base + t;
        int v = (idx < N) ? count[idx] : 0;
        sdata[t] = v;
        __syncthreads();
        for (int off = 1; off < 1024; off <<= 1) {
            int add = (t >= off) ? sdata[t - off] : 0;
            __syncthreads();
            sdata[t] += add;
            __syncthreads();
        }
        if (idx < N) rowptr[idx + 1] = carry_s + sdata[t];
        __syncthreads();
        if (t == 0) carry_s += sdata[1023];
        __syncthreads();
    }
}

__global__ void scatter_kernel(const int* __restrict__ src, const int* __restrict__ dst,
                               const int* __restrict__ rowptr, int* __restrict__ cursor,
                               int* __restrict__ srcperm, int E)
{
    int e = blockIdx.x * blockDim.x + threadIdx.x;
    if (e < E) {
        int d = dst[e];
        int pos = rowptr[d] + atomicAdd(&cursor[d], 1);
        srcperm[pos] = src[e];
    }
}

// ---------------- Attention: edge-parallel, one block (128 thr) per node ----
// qkv packed bf16 [N][384] (q|k|v). Chunks of 128 edges, online softmax.
// Phase A: thread t = edge t of chunk, computes all 4 head dots (parallel gathers).
// Phase B: 32-lane group per head: max / exp / denom (online rescale).
// Phase C: thread t = (head t>>5, dim t&31): V aggregation, 4-way unrolled ILP.
__global__ __launch_bounds__(128)
void attn_kernel(const __hip_bfloat16* __restrict__ qkv, const int* __restrict__ rowptr,
                 const int* __restrict__ srcperm, __hip_bfloat16* __restrict__ agg)
{
    __shared__ float q_s[128];
    __shared__ float a_s[128][5];    // alpha, then reused as softmax weights
    __shared__ int   j_s[128];
    int i = blockIdx.x;
    int t = threadIdx.x;
    int beg = rowptr[i], end = rowptr[i + 1], deg = end - beg;
    const float scale = 0.17677669529663687f; // 1/sqrt(32)

    q_s[t] = b2f(((const short*)qkv)[(size_t)i * QKVC + t]);
    __syncthreads();

    int h = t >> 5, d = t & 31;
    float m_run = -3.4e38f, d_run = 0.f, accv = 0.f;

    for (int c0 = 0; c0 < deg; c0 += 128) {
        int cn = min(128, deg - c0);
        // ---- Phase A: parallel alpha ----
        if (t < cn) {
            int j = srcperm[beg + c0 + t];
            j_s[t] = j;
            const short* kr = (const short*)qkv + (size_t)j * QKVC + 128;
#pragma unroll
            for (int hh = 0; hh < 4; ++hh) {
                float dot = 0.f;
#pragma unroll
                for (int c = 0; c < 4; ++c) {
                    bf16frag kv = *(const bf16frag*)(kr + hh * 32 + c * 8);
#pragma unroll
                    for (int e = 0; e < 8; ++e)
                        dot += q_s[hh * 32 + c * 8 + e] * b2f(kv[e]);
                }
                a_s[t][hh] = dot * scale;
            }
        }
        __syncthreads();

        // ---- Phase B: per-head online softmax ----
        float cm = -3.4e38f;
        for (int p = d; p < cn; p += 32) cm = fmaxf(cm, a_s[p][h]);
#pragma unroll
        for (int off = 16; off; off >>= 1) cm = fmaxf(cm, __shfl_xor(cm, off, 32));
        float m_new = fmaxf(m_run, cm);
        float rescale = expf(m_run - m_new);
        float dsum = 0.f;
        for (int p = d; p < cn; p += 32) {
            float ex = expf(a_s[p][h] - m_new);
            a_s[p][h] = ex;
            dsum += ex;
        }
#pragma unroll
        for (int off = 16; off; off >>= 1) dsum += __shfl_xor(dsum, off, 32);
        d_run = d_run * rescale + dsum;
        m_run = m_new;
        accv *= rescale;
        __syncthreads();

        // ---- Phase C: V aggregation (vo = 256 + t since h*32+d == t) ----
        const short* vb = (const short*)qkv;
        int vo = 256 + t;
        int p = 0;
        for (; p + 4 <= cn; p += 4) {
            int j0 = j_s[p], j1 = j_s[p + 1], j2 = j_s[p + 2], j3 = j_s[p + 3];
            float w0 = a_s[p][h], w1 = a_s[p + 1][h];
            float w2 = a_s[p + 2][h], w3 = a_s[p + 3][h];
            float v0 = b2f(vb[(size_t)j0 * QKVC + vo]);
            float v1 = b2f(vb[(size_t)j1 * QKVC + vo]);
            float v2 = b2f(vb[(size_t)j2 * QKVC + vo]);
            float v3 = b2f(vb[(size_t)j3 * QKVC + vo]);
            accv += w0 * v0; accv += w1 * v1; accv += w2 * v2; accv += w3 * v3;
        }
        for (; p < cn; ++p)
            accv += a_s[p][h] * b2f(vb[(size_t)j_s[p] * QKVC + vo]);
        __syncthreads();
    }
    agg[(size_t)i * INNERC + t] = __float2bfloat16(accv / (d_run + 1e-16f));
}

// ---------------- Launch ----------------
extern "C" void kernel_launch(void* const* d_in, const int* in_sizes, int n_in,
                              void* d_out, int out_size, void* d_ws, size_t ws_size,
                              hipStream_t stream)
{
    const float* x    = (const float*)d_in[0];
    const int*   ei   = (const int*)  d_in[1];
    const float* ln1g = (const float*)d_in[2];
    const float* ln1b = (const float*)d_in[3];
    const float* wq   = (const float*)d_in[4];
    const float* bq   = (const float*)d_in[5];
    const float* wk   = (const float*)d_in[6];
    const float* bk   = (const float*)d_in[7];
    const float* wv   = (const float*)d_in[8];
    const float* bv   = (const float*)d_in[9];
    const float* wo   = (const float*)d_in[10];
    const float* bo   = (const float*)d_in[11];
    const float* ln2g = (const float*)d_in[12];
    const float* ln2b = (const float*)d_in[13];
    const float* w1   = (const float*)d_in[14];
    const float* b1   = (const float*)d_in[15];
    const float* w2   = (const float*)d_in[16];
    const float* b2   = (const float*)d_in[17];

    const int N = in_sizes[0] / DIMC;   // 20000
    const int E = in_sizes[1] / 2;      // 320000
    const int* srcIdx = ei;
    const int* dstIdx = ei + E;

    char* p = (char*)d_ws;
    auto alloc = [&](size_t bytes) {
        char* r = p;
        p += (bytes + 255) & ~(size_t)255;
        return r;
    };
    float*          xbuf   = (float*)alloc((size_t)N * DIMC * 4);
    __hip_bfloat16* h      = (__hip_bfloat16*)alloc((size_t)N * DIMC * 2);
    __hip_bfloat16* qkv    = (__hip_bfloat16*)alloc((size_t)N * QKVC * 2);
    __hip_bfloat16* agg    = (__hip_bfloat16*)alloc((size_t)N * INNERC * 2);
    __hip_bfloat16* u      = (__hip_bfloat16*)alloc((size_t)N * 1024 * 2);
    int*            rowptr = (int*)alloc((size_t)(N + 1) * 4);
    int*            cnt    = (int*)alloc((size_t)N * 4);
    int*            srcperm= (int*)alloc((size_t)E * 4);
    __hip_bfloat16* wqkvB  = (__hip_bfloat16*)alloc((size_t)4 * QKVC * DIMC * 2);
    float*          bqkvF  = (float*)alloc((size_t)4 * QKVC * 4);
    __hip_bfloat16* woB    = (__hip_bfloat16*)alloc((size_t)4 * DIMC * INNERC * 2);
    __hip_bfloat16* w1B    = (__hip_bfloat16*)alloc((size_t)4 * 1024 * DIMC * 2);
    __hip_bfloat16* w2B    = (__hip_bfloat16*)alloc((size_t)4 * DIMC * 1024 * 2);

    // Weight conversion (per-call, deterministic)
    packqkv_kernel<<<4 * QKVC, 256, 0, stream>>>(wq, wk, wv, bq, bk, bv, wqkvB, bqkvF);
    {
        int n = 4 * DIMC * INNERC;
        f2b_kernel<<<(n / 4 + 255) / 256, 256, 0, stream>>>(wo, woB, n);
        n = 4 * 1024 * DIMC;
        f2b_kernel<<<(n / 4 + 255) / 256, 256, 0, stream>>>(w1, w1B, n);
        f2b_kernel<<<(n / 4 + 255) / 256, 256, 0, stream>>>(w2, w2B, n);
    }

    // CSR build
    hipMemsetAsync(cnt, 0, (size_t)N * 4, stream);
    count_kernel<<<(E + 255) / 256, 256, 0, stream>>>(dstIdx, cnt, E);
    scan_kernel<<<1, 1024, 0, stream>>>(cnt, rowptr, N);
    hipMemsetAsync(cnt, 0, (size_t)N * 4, stream);
    scatter_kernel<<<(E + 255) / 256, 256, 0, stream>>>(srcIdx, dstIdx, rowptr, cnt, srcperm, E);

    int mt = (N + 127) / 128;   // 157
    for (int l = 0; l < 4; ++l) {
        const float* xin = (l == 0) ? x : xbuf;
        ln_kernel<<<N, 256, 0, stream>>>(xin, ln1g + l * DIMC, ln1b + l * DIMC, h);
        mfma_gemm<0><<<dim3(mt, QKVC / 128), 256, 0, stream>>>(
            h, wqkvB + (size_t)l * QKVC * DIMC, bqkvF + l * QKVC, nullptr,
            qkv, N, DIMC, QKVC);
        attn_kernel<<<N, 128, 0, stream>>>(qkv, rowptr, srcperm, agg);
        mfma_gemm<2><<<dim3(mt, DIMC / 128), 256, 0, stream>>>(
            agg, woB + (size_t)l * DIMC * INNERC, bo + l * DIMC, xin,
            xbuf, N, INNERC, DIMC);
        ln_kernel<<<N, 256, 0, stream>>>(xbuf, ln2g + l * DIMC, ln2b + l * DIMC, h);
        mfma_gemm<1><<<dim3(mt, 1024 / 128), 256, 0, stream>>>(
            h, w1B + (size_t)l * 1024 * DIMC, b1 + l * 1024, nullptr,
            u, N, DIMC, 1024);
        float* xout = (l == 3) ? (float*)d_out : xbuf;
        mfma_gemm<2><<<dim3(mt, DIMC / 128), 256, 0, stream>>>(
            u, w2B + (size_t)l * DIMC * 1024, b2 + l * DIMC, xbuf,
            xout, N, 1024, DIMC);
    }
}

// Round 4
// 779.001 us; speedup vs baseline: 3.7643x; 1.0005x over previous
//
#include <hip/hip_runtime.h>
#include <hip/hip_bf16.h>
#include <math.h>

#define DIMC 256
#define INNERC 128
#define HEADSC 4
#define DHC 32
#define QKVC 384

typedef __attribute__((ext_vector_type(8))) short bf16frag;   // 8 bf16 = 4 VGPRs
typedef __attribute__((ext_vector_type(4))) float f32x4;

__device__ __forceinline__ float gelu_exact(float x) {
    return 0.5f * x * (1.0f + erff(x * 0.70710678118654752f));
}

__device__ __forceinline__ float b2f(short s) {
    return __uint_as_float(((unsigned)(unsigned short)s) << 16);
}

__device__ __forceinline__ void gload_lds16(const void* g, void* l) {
    __builtin_amdgcn_global_load_lds(
        (const __attribute__((address_space(1))) void*)g,
        (__attribute__((address_space(3))) void*)l, 16, 0, 0);
}

// ---------------- LayerNorm: fp32 in, bf16 out ----------------
__global__ __launch_bounds__(256)
void ln_kernel(const float* __restrict__ x, const float* __restrict__ g,
               const float* __restrict__ b, __hip_bfloat16* __restrict__ out)
{
    int i = blockIdx.x;
    int t = threadIdx.x;
    float v = x[(size_t)i * DIMC + t];
    __shared__ float red[4];
    float s = v;
#pragma unroll
    for (int off = 32; off; off >>= 1) s += __shfl_xor(s, off);
    if ((t & 63) == 0) red[t >> 6] = s;
    __syncthreads();
    float mean = (red[0] + red[1] + red[2] + red[3]) * (1.f / DIMC);
    float c = v - mean;
    float s2 = c * c;
#pragma unroll
    for (int off = 32; off; off >>= 1) s2 += __shfl_xor(s2, off);
    __syncthreads();
    if ((t & 63) == 0) red[t >> 6] = s2;
    __syncthreads();
    float var = (red[0] + red[1] + red[2] + red[3]) * (1.f / DIMC);
    out[(size_t)i * DIMC + t] =
        __float2bfloat16(c * rsqrtf(var + 1e-5f) * g[t] + b[t]);
}

// ---------------- fp32 -> bf16 convert (n % 4 == 0) ----------------
__global__ void f2b_kernel(const float* __restrict__ src,
                           __hip_bfloat16* __restrict__ dst, int n)
{
    int i = (blockIdx.x * blockDim.x + threadIdx.x) * 4;
    if (i < n) {
        float4 v = *(const float4*)(src + i);
        dst[i + 0] = __float2bfloat16(v.x);
        dst[i + 1] = __float2bfloat16(v.y);
        dst[i + 2] = __float2bfloat16(v.z);
        dst[i + 3] = __float2bfloat16(v.w);
    }
}

// ---------------- pack wq/wk/wv -> wqkv bf16 [4][384][256], biases [4][384] ----
__global__ __launch_bounds__(256)
void packqkv_kernel(const float* __restrict__ wq, const float* __restrict__ wk,
                    const float* __restrict__ wv, const float* __restrict__ bq,
                    const float* __restrict__ bk, const float* __restrict__ bv,
                    __hip_bfloat16* __restrict__ wqkv, float* __restrict__ bqkv)
{
    int row = blockIdx.x;                 // 0 .. 4*384-1
    int l = row / QKVC, c = row % QKVC;
    int which = c >> 7, cc = c & 127;
    const float* srcw = which == 0 ? wq : which == 1 ? wk : wv;
    const float* srcb = which == 0 ? bq : which == 1 ? bk : bv;
    srcw += ((size_t)l * INNERC + cc) * DIMC;
    wqkv[(size_t)row * DIMC + threadIdx.x] = __float2bfloat16(srcw[threadIdx.x]);
    if (threadIdx.x == 0) bqkv[row] = srcb[l * INNERC + cc];
}

// ---------------- MFMA GEMM: C[M][OUT] = A[M][K] @ W[OUT][K]^T + bias --------
template<int EPI>
__global__ __launch_bounds__(256)
void mfma_gemm(const __hip_bfloat16* __restrict__ A,
               const __hip_bfloat16* __restrict__ W,
               const float* __restrict__ bias, const float* __restrict__ res,
               void* __restrict__ Cout, int M, int K, int OUT)
{
    __shared__ char lds[128 * 64 * 2 * 2];          // A tile 16KB + B tile 16KB
    char* As = lds;
    char* Ws = lds + 128 * 64 * 2;
    int tid = threadIdx.x;
    int lane = tid & 63;
    int w = tid >> 6;
    int wr = w >> 1, wc = w & 1;
    int bm = blockIdx.x * 128, bn = blockIdx.y * 128;

    f32x4 acc[4][4] = {};

    for (int k0 = 0; k0 < K; k0 += 64) {
#pragma unroll
        for (int it = 0; it < 4; ++it) {
            int chunk = it * 256 + tid;
            int r = chunk >> 3;                      // tile row 0..127
            int sc = (chunk & 7) ^ (r & 7);          // inverse-swizzled src chunk
            int grow = bm + r;
            if (grow < M)                            // wave-uniform (M%8==0)
                gload_lds16((const char*)A + ((size_t)grow * K + k0) * 2 + sc * 16,
                            As + chunk * 16);
            gload_lds16((const char*)W + ((size_t)(bn + r) * K + k0) * 2 + sc * 16,
                        Ws + chunk * 16);
        }
        __syncthreads();

#pragma unroll
        for (int s = 0; s < 2; ++s) {
            bf16frag af[4], bfr[4];
            int kb = s * 64 + ((lane >> 4) << 4);    // byte offset in row
#pragma unroll
            for (int m = 0; m < 4; ++m) {
                int ar = wr * 64 + m * 16 + (lane & 15);
                af[m] = *(const bf16frag*)(As + ar * 128 + (kb ^ ((ar & 7) << 4)));
            }
#pragma unroll
            for (int n = 0; n < 4; ++n) {
                int br = wc * 64 + n * 16 + (lane & 15);
                bfr[n] = *(const bf16frag*)(Ws + br * 128 + (kb ^ ((br & 7) << 4)));
            }
#pragma unroll
            for (int m = 0; m < 4; ++m)
#pragma unroll
                for (int n = 0; n < 4; ++n)
                    acc[m][n] = __builtin_amdgcn_mfma_f32_16x16x32_bf16(
                        af[m], bfr[n], acc[m][n], 0, 0, 0);
        }
        __syncthreads();
    }

#pragma unroll
    for (int m = 0; m < 4; ++m)
#pragma unroll
        for (int r = 0; r < 4; ++r) {
            int grow = bm + wr * 64 + m * 16 + ((lane >> 4) << 2) + r;
            if (grow < M) {
#pragma unroll
                for (int n = 0; n < 4; ++n) {
                    int gcol = bn + wc * 64 + n * 16 + (lane & 15);
                    float val = acc[m][n][r] + bias[gcol];
                    if (EPI == 1) val = gelu_exact(val);
                    if (EPI == 2) {
                        val += res[(size_t)grow * OUT + gcol];
                        ((float*)Cout)[(size_t)grow * OUT + gcol] = val;
                    } else {
                        ((__hip_bfloat16*)Cout)[(size_t)grow * OUT + gcol] =
                            __float2bfloat16(val);
                    }
                }
            }
        }
}

// ---------------- CSR build ----------------
__global__ void count_kernel(const int* __restrict__ dst, int* __restrict__ count, int E)
{
    int e = blockIdx.x * blockDim.x + threadIdx.x;
    if (e < E) atomicAdd(&count[dst[e]], 1);
}

__global__ __launch_bounds__(1024)
void scan_kernel(const int* __restrict__ count, int* __restrict__ rowptr, int N)
{
    __shared__ int sdata[1024];
    __shared__ int carry_s;
    int t = threadIdx.x;
    if (t == 0) { carry_s = 0; rowptr[0] = 0; }
    __syncthreads();
    for (int base = 0; base < N; base += 1024) {
        int idx = base + t;
        int v = (idx < N) ? count[idx] : 0;
        sdata[t] = v;
        __syncthreads();
        for (int off = 1; off < 1024; off <<= 1) {
            int add = (t >= off) ? sdata[t - off] : 0;
            __syncthreads();
            sdata[t] += add;
            __syncthreads();
        }
        if (idx < N) rowptr[idx + 1] = carry_s + sdata[t];
        __syncthreads();
        if (t == 0) carry_s += sdata[1023];
        __syncthreads();
    }
}

__global__ void scatter_kernel(const int* __restrict__ src, const int* __restrict__ dst,
                               const int* __restrict__ rowptr, int* __restrict__ cursor,
                               int* __restrict__ srcperm, int E)
{
    int e = blockIdx.x * blockDim.x + threadIdx.x;
    if (e < E) {
        int d = dst[e];
        int pos = rowptr[d] + atomicAdd(&cursor[d], 1);
        srcperm[pos] = src[e];
    }
}

// ---------------- Attention: one WAVE per node, no __syncthreads ------------
// Lane = h*16 + u. Chunk of 16 edges: lane computes 32-dim dot for edge u,
// head h. Per-head softmax via shfl_xor masks 1/2/4/8 (16-lane groups).
// V phase: lane (h,u) owns output dims h*32+2u, h*32+2u+1 (one 4B load per
// edge; wave covers the full 256B V row). Online softmax over chunks.
__global__ __launch_bounds__(256)
void attn_kernel(const __hip_bfloat16* __restrict__ qkv, const int* __restrict__ rowptr,
                 const int* __restrict__ srcperm, __hip_bfloat16* __restrict__ agg,
                 int N)
{
    int wid = (blockIdx.x * 256 + threadIdx.x) >> 6;   // node index
    if (wid >= N) return;
    int lane = threadIdx.x & 63;
    int h = lane >> 4, u = lane & 15;
    int i = wid;
    int beg = rowptr[i], end = rowptr[i + 1], deg = end - beg;
    const short* base = (const short*)qkv;
    const float scale = 0.17677669529663687f; // 1/sqrt(32)

    // Q fragment for this lane's head (4 x bf16x8 = 32 dims)
    bf16frag qf[4];
    const short* qr = base + (size_t)i * QKVC + h * 32;
#pragma unroll
    for (int c = 0; c < 4; ++c) qf[c] = *(const bf16frag*)(qr + c * 8);

    float m_run = -3.4e38f, d_run = 0.f;
    float accx = 0.f, accy = 0.f;     // output dims h*32+2u, h*32+2u+1

    for (int c0 = 0; c0 < deg; c0 += 16) {
        int cn = min(16, deg - c0);
        // ---- alpha for edge slot u, head h ----
        bool valid = (u < cn);
        int j = valid ? srcperm[beg + c0 + u] : 0;
        float dot = 0.f;
        const short* kr = base + (size_t)j * QKVC + 128 + h * 32;
#pragma unroll
        for (int c = 0; c < 4; ++c) {
            bf16frag kv = *(const bf16frag*)(kr + c * 8);
#pragma unroll
            for (int e = 0; e < 8; ++e)
                dot += b2f(qf[c][e]) * b2f(kv[e]);
        }
        float alpha = valid ? dot * scale : -3.4e38f;

        // ---- per-head online softmax (16-lane group reduce) ----
        float cm = alpha;
#pragma unroll
        for (int off = 8; off; off >>= 1) cm = fmaxf(cm, __shfl_xor(cm, off));
        float m_new = fmaxf(m_run, cm);
        float rescale = expf(m_run - m_new);
        float w = valid ? expf(alpha - m_new) : 0.f;
        float dsum = w;
#pragma unroll
        for (int off = 8; off; off >>= 1) dsum += __shfl_xor(dsum, off);
        d_run = d_run * rescale + dsum;
        m_run = m_new;
        accx *= rescale;
        accy *= rescale;

        // ---- V aggregation: broadcast (w, j) from lane h*16+e ----
        for (int e = 0; e < cn; ++e) {
            float we = __shfl(w, h * 16 + e);
            int je = __shfl(j, h * 16 + e);
            unsigned vw = *(const unsigned*)(base + (size_t)je * QKVC + 256 + h * 32 + u * 2);
            accx += we * b2f((short)(vw & 0xffff));
            accy += we * b2f((short)(vw >> 16));
        }
    }

    float inv = 1.f / (d_run + 1e-16f);
    __hip_bfloat16* outp = agg + (size_t)i * INNERC + h * 32 + u * 2;
    outp[0] = __float2bfloat16(accx * inv);
    outp[1] = __float2bfloat16(accy * inv);
}

// ---------------- Launch ----------------
extern "C" void kernel_launch(void* const* d_in, const int* in_sizes, int n_in,
                              void* d_out, int out_size, void* d_ws, size_t ws_size,
                              hipStream_t stream)
{
    const float* x    = (const float*)d_in[0];
    const int*   ei   = (const int*)  d_in[1];
    const float* ln1g = (const float*)d_in[2];
    const float* ln1b = (const float*)d_in[3];
    const float* wq   = (const float*)d_in[4];
    const float* bq   = (const float*)d_in[5];
    const float* wk   = (const float*)d_in[6];
    const float* bk   = (const float*)d_in[7];
    const float* wv   = (const float*)d_in[8];
    const float* bv   = (const float*)d_in[9];
    const float* wo   = (const float*)d_in[10];
    const float* bo   = (const float*)d_in[11];
    const float* ln2g = (const float*)d_in[12];
    const float* ln2b = (const float*)d_in[13];
    const float* w1   = (const float*)d_in[14];
    const float* b1   = (const float*)d_in[15];
    const float* w2   = (const float*)d_in[16];
    const float* b2   = (const float*)d_in[17];

    const int N = in_sizes[0] / DIMC;   // 20000
    const int E = in_sizes[1] / 2;      // 320000
    const int* srcIdx = ei;
    const int* dstIdx = ei + E;

    char* p = (char*)d_ws;
    auto alloc = [&](size_t bytes) {
        char* r = p;
        p += (bytes + 255) & ~(size_t)255;
        return r;
    };
    float*          xbuf   = (float*)alloc((size_t)N * DIMC * 4);
    __hip_bfloat16* h      = (__hip_bfloat16*)alloc((size_t)N * DIMC * 2);
    __hip_bfloat16* qkv    = (__hip_bfloat16*)alloc((size_t)N * QKVC * 2);
    __hip_bfloat16* agg    = (__hip_bfloat16*)alloc((size_t)N * INNERC * 2);
    __hip_bfloat16* u      = (__hip_bfloat16*)alloc((size_t)N * 1024 * 2);
    int*            rowptr = (int*)alloc((size_t)(N + 1) * 4);
    int*            cnt    = (int*)alloc((size_t)N * 4);
    int*            srcperm= (int*)alloc((size_t)E * 4);
    __hip_bfloat16* wqkvB  = (__hip_bfloat16*)alloc((size_t)4 * QKVC * DIMC * 2);
    float*          bqkvF  = (float*)alloc((size_t)4 * QKVC * 4);
    __hip_bfloat16* woB    = (__hip_bfloat16*)alloc((size_t)4 * DIMC * INNERC * 2);
    __hip_bfloat16* w1B    = (__hip_bfloat16*)alloc((size_t)4 * 1024 * DIMC * 2);
    __hip_bfloat16* w2B    = (__hip_bfloat16*)alloc((size_t)4 * DIMC * 1024 * 2);

    // Weight conversion (per-call, deterministic)
    packqkv_kernel<<<4 * QKVC, 256, 0, stream>>>(wq, wk, wv, bq, bk, bv, wqkvB, bqkvF);
    {
        int n = 4 * DIMC * INNERC;
        f2b_kernel<<<(n / 4 + 255) / 256, 256, 0, stream>>>(wo, woB, n);
        n = 4 * 1024 * DIMC;
        f2b_kernel<<<(n / 4 + 255) / 256, 256, 0, stream>>>(w1, w1B, n);
        f2b_kernel<<<(n / 4 + 255) / 256, 256, 0, stream>>>(w2, w2B, n);
    }

    // CSR build
    hipMemsetAsync(cnt, 0, (size_t)N * 4, stream);
    count_kernel<<<(E + 255) / 256, 256, 0, stream>>>(dstIdx, cnt, E);
    scan_kernel<<<1, 1024, 0, stream>>>(cnt, rowptr, N);
    hipMemsetAsync(cnt, 0, (size_t)N * 4, stream);
    scatter_kernel<<<(E + 255) / 256, 256, 0, stream>>>(srcIdx, dstIdx, rowptr, cnt, srcperm, E);

    int mt = (N + 127) / 128;   // 157
    int attnBlocks = (N * 64 + 255) / 256;   // one wave per node
    for (int l = 0; l < 4; ++l) {
        const float* xin = (l == 0) ? x : xbuf;
        ln_kernel<<<N, 256, 0, stream>>>(xin, ln1g + l * DIMC, ln1b + l * DIMC, h);
        mfma_gemm<0><<<dim3(mt, QKVC / 128), 256, 0, stream>>>(
            h, wqkvB + (size_t)l * QKVC * DIMC, bqkvF + l * QKVC, nullptr,
            qkv, N, DIMC, QKVC);
        attn_kernel<<<attnBlocks, 256, 0, stream>>>(qkv, rowptr, srcperm, agg, N);
        mfma_gemm<2><<<dim3(mt, DIMC / 128), 256, 0, stream>>>(
            agg, woB + (size_t)l * DIMC * INNERC, bo + l * DIMC, xin,
            xbuf, N, INNERC, DIMC);
        ln_kernel<<<N, 256, 0, stream>>>(xbuf, ln2g + l * DIMC, ln2b + l * DIMC, h);
        mfma_gemm<1><<<dim3(mt, 1024 / 128), 256, 0, stream>>>(
            h, w1B + (size_t)l * 1024 * DIMC, b1 + l * 1024, nullptr,
            u, N, DIMC, 1024);
        float* xout = (l == 3) ? (float*)d_out : xbuf;
        mfma_gemm<2><<<dim3(mt, DIMC / 128), 256, 0, stream>>>(
            u, w2B + (size_t)l * DIMC * 1024, b2 + l * DIMC, xbuf,
            xout, N, 1024, DIMC);
    }
}

// Round 5
// 698.656 us; speedup vs baseline: 4.1972x; 1.1150x over previous
//
#include <hip/hip_runtime.h>
#include <hip/hip_bf16.h>
#include <math.h>

#define DIMC 256
#define INNERC 128
#define HEADSC 4
#define DHC 32
#define QKVC 384

typedef __attribute__((ext_vector_type(8))) short bf16frag;   // 8 bf16 = 4 VGPRs
typedef __attribute__((ext_vector_type(4))) float f32x4;

__device__ __forceinline__ float gelu_exact(float x) {
    return 0.5f * x * (1.0f + erff(x * 0.70710678118654752f));
}

__device__ __forceinline__ float b2f(short s) {
    return __uint_as_float(((unsigned)(unsigned short)s) << 16);
}

__device__ __forceinline__ void gload_lds16(const void* g, void* l) {
    __builtin_amdgcn_global_load_lds(
        (const __attribute__((address_space(1))) void*)g,
        (__attribute__((address_space(3))) void*)l, 16, 0, 0);
}

// ---------------- LayerNorm: fp32 in, bf16 out ----------------
__global__ __launch_bounds__(256)
void ln_kernel(const float* __restrict__ x, const float* __restrict__ g,
               const float* __restrict__ b, __hip_bfloat16* __restrict__ out)
{
    int i = blockIdx.x;
    int t = threadIdx.x;
    float v = x[(size_t)i * DIMC + t];
    __shared__ float red[4];
    float s = v;
#pragma unroll
    for (int off = 32; off; off >>= 1) s += __shfl_xor(s, off);
    if ((t & 63) == 0) red[t >> 6] = s;
    __syncthreads();
    float mean = (red[0] + red[1] + red[2] + red[3]) * (1.f / DIMC);
    float c = v - mean;
    float s2 = c * c;
#pragma unroll
    for (int off = 32; off; off >>= 1) s2 += __shfl_xor(s2, off);
    __syncthreads();
    if ((t & 63) == 0) red[t >> 6] = s2;
    __syncthreads();
    float var = (red[0] + red[1] + red[2] + red[3]) * (1.f / DIMC);
    out[(size_t)i * DIMC + t] =
        __float2bfloat16(c * rsqrtf(var + 1e-5f) * g[t] + b[t]);
}

// ---------------- fp32 -> bf16 convert (n % 4 == 0) ----------------
__global__ void f2b_kernel(const float* __restrict__ src,
                           __hip_bfloat16* __restrict__ dst, int n)
{
    int i = (blockIdx.x * blockDim.x + threadIdx.x) * 4;
    if (i < n) {
        float4 v = *(const float4*)(src + i);
        dst[i + 0] = __float2bfloat16(v.x);
        dst[i + 1] = __float2bfloat16(v.y);
        dst[i + 2] = __float2bfloat16(v.z);
        dst[i + 3] = __float2bfloat16(v.w);
    }
}

// ---------------- pack wq/wk/wv -> wqkv bf16 [4][384][256], biases [4][384] ----
__global__ __launch_bounds__(256)
void packqkv_kernel(const float* __restrict__ wq, const float* __restrict__ wk,
                    const float* __restrict__ wv, const float* __restrict__ bq,
                    const float* __restrict__ bk, const float* __restrict__ bv,
                    __hip_bfloat16* __restrict__ wqkv, float* __restrict__ bqkv)
{
    int row = blockIdx.x;                 // 0 .. 4*384-1
    int l = row / QKVC, c = row % QKVC;
    int which = c >> 7, cc = c & 127;
    const float* srcw = which == 0 ? wq : which == 1 ? wk : wv;
    const float* srcb = which == 0 ? bq : which == 1 ? bk : bv;
    srcw += ((size_t)l * INNERC + cc) * DIMC;
    wqkv[(size_t)row * DIMC + threadIdx.x] = __float2bfloat16(srcw[threadIdx.x]);
    if (threadIdx.x == 0) bqkv[row] = srcb[l * INNERC + cc];
}

// ---------------- MFMA GEMM: C[M][OUT] = A[M][K] @ W[OUT][K]^T + bias --------
template<int EPI>
__global__ __launch_bounds__(256)
void mfma_gemm(const __hip_bfloat16* __restrict__ A,
               const __hip_bfloat16* __restrict__ W,
               const float* __restrict__ bias, const float* __restrict__ res,
               void* __restrict__ Cout, int M, int K, int OUT)
{
    __shared__ char lds[128 * 64 * 2 * 2];          // A tile 16KB + B tile 16KB
    char* As = lds;
    char* Ws = lds + 128 * 64 * 2;
    int tid = threadIdx.x;
    int lane = tid & 63;
    int w = tid >> 6;
    int wr = w >> 1, wc = w & 1;
    int bm = blockIdx.x * 128, bn = blockIdx.y * 128;

    f32x4 acc[4][4] = {};

    for (int k0 = 0; k0 < K; k0 += 64) {
#pragma unroll
        for (int it = 0; it < 4; ++it) {
            int chunk = it * 256 + tid;
            int r = chunk >> 3;                      // tile row 0..127
            int sc = (chunk & 7) ^ (r & 7);          // inverse-swizzled src chunk
            int grow = bm + r;
            if (grow < M)                            // wave-uniform (M%8==0)
                gload_lds16((const char*)A + ((size_t)grow * K + k0) * 2 + sc * 16,
                            As + chunk * 16);
            gload_lds16((const char*)W + ((size_t)(bn + r) * K + k0) * 2 + sc * 16,
                        Ws + chunk * 16);
        }
        __syncthreads();

#pragma unroll
        for (int s = 0; s < 2; ++s) {
            bf16frag af[4], bfr[4];
            int kb = s * 64 + ((lane >> 4) << 4);    // byte offset in row
#pragma unroll
            for (int m = 0; m < 4; ++m) {
                int ar = wr * 64 + m * 16 + (lane & 15);
                af[m] = *(const bf16frag*)(As + ar * 128 + (kb ^ ((ar & 7) << 4)));
            }
#pragma unroll
            for (int n = 0; n < 4; ++n) {
                int br = wc * 64 + n * 16 + (lane & 15);
                bfr[n] = *(const bf16frag*)(Ws + br * 128 + (kb ^ ((br & 7) << 4)));
            }
#pragma unroll
            for (int m = 0; m < 4; ++m)
#pragma unroll
                for (int n = 0; n < 4; ++n)
                    acc[m][n] = __builtin_amdgcn_mfma_f32_16x16x32_bf16(
                        af[m], bfr[n], acc[m][n], 0, 0, 0);
        }
        __syncthreads();
    }

#pragma unroll
    for (int m = 0; m < 4; ++m)
#pragma unroll
        for (int r = 0; r < 4; ++r) {
            int grow = bm + wr * 64 + m * 16 + ((lane >> 4) << 2) + r;
            if (grow < M) {
#pragma unroll
                for (int n = 0; n < 4; ++n) {
                    int gcol = bn + wc * 64 + n * 16 + (lane & 15);
                    float val = acc[m][n][r] + bias[gcol];
                    if (EPI == 1) val = gelu_exact(val);
                    if (EPI == 2) {
                        val += res[(size_t)grow * OUT + gcol];
                        ((float*)Cout)[(size_t)grow * OUT + gcol] = val;
                    } else {
                        ((__hip_bfloat16*)Cout)[(size_t)grow * OUT + gcol] =
                            __float2bfloat16(val);
                    }
                }
            }
        }
}

// ---------------- CSR build ----------------
__global__ void count_kernel(const int* __restrict__ dst, int* __restrict__ count, int E)
{
    int e = blockIdx.x * blockDim.x + threadIdx.x;
    if (e < E) atomicAdd(&count[dst[e]], 1);
}

__global__ __launch_bounds__(1024)
void scan_kernel(const int* __restrict__ count, int* __restrict__ rowptr, int N)
{
    __shared__ int sdata[1024];
    __shared__ int carry_s;
    int t = threadIdx.x;
    if (t == 0) { carry_s = 0; rowptr[0] = 0; }
    __syncthreads();
    for (int base = 0; base < N; base += 1024) {
        int idx = base + t;
        int v = (idx < N) ? count[idx] : 0;
        sdata[t] = v;
        __syncthreads();
        for (int off = 1; off < 1024; off <<= 1) {
            int add = (t >= off) ? sdata[t - off] : 0;
            __syncthreads();
            sdata[t] += add;
            __syncthreads();
        }
        if (idx < N) rowptr[idx + 1] = carry_s + sdata[t];
        __syncthreads();
        if (t == 0) carry_s += sdata[1023];
        __syncthreads();
    }
}

__global__ void scatter_kernel(const int* __restrict__ src, const int* __restrict__ dst,
                               const int* __restrict__ rowptr, int* __restrict__ cursor,
                               int* __restrict__ srcperm, int E)
{
    int e = blockIdx.x * blockDim.x + threadIdx.x;
    if (e < E) {
        int d = dst[e];
        int pos = rowptr[d] + atomicAdd(&cursor[d], 1);
        srcperm[pos] = src[e];
    }
}

// ---------------- Attention: one WAVE per node, ILP-restructured ------------
// Lane = h*16 + u. Chunk of 16 edges. Invalid slots carry j=i (safe hot row)
// and w=0. V phase is a fixed-16 branchless unroll: 16 independent gathers in
// flight, then 32 fmas. Next chunk's srcperm prefetched during current chunk.
__global__ __launch_bounds__(256)
void attn_kernel(const __hip_bfloat16* __restrict__ qkv, const int* __restrict__ rowptr,
                 const int* __restrict__ srcperm, __hip_bfloat16* __restrict__ agg,
                 int N)
{
    int wid = (blockIdx.x * 256 + threadIdx.x) >> 6;   // node index
    if (wid >= N) return;
    int lane = threadIdx.x & 63;
    int h = lane >> 4, u = lane & 15;
    int i = wid;
    int beg = rowptr[i], deg = rowptr[i + 1] - beg;
    const short* base = (const short*)qkv;
    const float scale = 0.17677669529663687f; // 1/sqrt(32)

    // Q fragment for this lane's head (4 x bf16x8 = 32 dims)
    bf16frag qf[4];
    const short* qr = base + (size_t)i * QKVC + h * 32;
#pragma unroll
    for (int c = 0; c < 4; ++c) qf[c] = *(const bf16frag*)(qr + c * 8);

    float m_run = -3.4e38f, d_run = 0.f;
    float accx = 0.f, accy = 0.f;     // output dims h*32+2u, h*32+2u+1

    // prefetch first chunk's edge index (invalid slots -> own row i)
    int j = (u < deg) ? srcperm[beg + u] : i;

    for (int c0 = 0; c0 < deg; c0 += 16) {
        int cn = min(16, deg - c0);
        bool valid = (u < cn);

        // ---- K gather (4 independent b128 loads) ----
        const short* kr = base + (size_t)j * QKVC + 128 + h * 32;
        bf16frag kf[4];
#pragma unroll
        for (int c = 0; c < 4; ++c) kf[c] = *(const bf16frag*)(kr + c * 8);

        // ---- prefetch next chunk's srcperm ----
        int nxt = c0 + 16 + u;
        int jn = (nxt < deg) ? srcperm[beg + nxt] : i;

        // ---- dot ----
        float dot = 0.f;
#pragma unroll
        for (int c = 0; c < 4; ++c)
#pragma unroll
            for (int e = 0; e < 8; ++e)
                dot += b2f(qf[c][e]) * b2f(kf[c][e]);
        float alpha = valid ? dot * scale : -3.4e38f;

        // ---- per-head online softmax (16-lane group reduce) ----
        float cm = alpha;
#pragma unroll
        for (int off = 8; off; off >>= 1) cm = fmaxf(cm, __shfl_xor(cm, off));
        float m_new = fmaxf(m_run, cm);
        float rescale = expf(m_run - m_new);
        float w = valid ? expf(alpha - m_new) : 0.f;
        float dsum = w;
#pragma unroll
        for (int off = 8; off; off >>= 1) dsum += __shfl_xor(dsum, off);
        d_run = d_run * rescale + dsum;
        m_run = m_new;
        accx *= rescale;
        accy *= rescale;

        // ---- V phase: branchless fixed-16 unroll, all gathers in flight ----
        float wes[16];
        unsigned vws[16];
#pragma unroll
        for (int e = 0; e < 16; ++e) {
            wes[e] = __shfl(w, h * 16 + e);
            int je = __shfl(j, h * 16 + e);        // invalid slots -> row i
            vws[e] = *(const unsigned*)(base + (size_t)je * QKVC + 256 + h * 32 + u * 2);
        }
#pragma unroll
        for (int e = 0; e < 16; ++e) {
            accx += wes[e] * b2f((short)(vws[e] & 0xffff));
            accy += wes[e] * b2f((short)(vws[e] >> 16));
        }
        j = jn;
    }

    float inv = 1.f / (d_run + 1e-16f);
    __hip_bfloat16* outp = agg + (size_t)i * INNERC + h * 32 + u * 2;
    outp[0] = __float2bfloat16(accx * inv);
    outp[1] = __float2bfloat16(accy * inv);
}

// ---------------- Launch ----------------
extern "C" void kernel_launch(void* const* d_in, const int* in_sizes, int n_in,
                              void* d_out, int out_size, void* d_ws, size_t ws_size,
                              hipStream_t stream)
{
    const float* x    = (const float*)d_in[0];
    const int*   ei   = (const int*)  d_in[1];
    const float* ln1g = (const float*)d_in[2];
    const float* ln1b = (const float*)d_in[3];
    const float* wq   = (const float*)d_in[4];
    const float* bq   = (const float*)d_in[5];
    const float* wk   = (const float*)d_in[6];
    const float* bk   = (const float*)d_in[7];
    const float* wv   = (const float*)d_in[8];
    const float* bv   = (const float*)d_in[9];
    const float* wo   = (const float*)d_in[10];
    const float* bo   = (const float*)d_in[11];
    const float* ln2g = (const float*)d_in[12];
    const float* ln2b = (const float*)d_in[13];
    const float* w1   = (const float*)d_in[14];
    const float* b1   = (const float*)d_in[15];
    const float* w2   = (const float*)d_in[16];
    const float* b2   = (const float*)d_in[17];

    const int N = in_sizes[0] / DIMC;   // 20000
    const int E = in_sizes[1] / 2;      // 320000
    const int* srcIdx = ei;
    const int* dstIdx = ei + E;

    char* p = (char*)d_ws;
    auto alloc = [&](size_t bytes) {
        char* r = p;
        p += (bytes + 255) & ~(size_t)255;
        return r;
    };
    float*          xbuf   = (float*)alloc((size_t)N * DIMC * 4);
    __hip_bfloat16* h      = (__hip_bfloat16*)alloc((size_t)N * DIMC * 2);
    __hip_bfloat16* qkv    = (__hip_bfloat16*)alloc((size_t)N * QKVC * 2);
    __hip_bfloat16* agg    = (__hip_bfloat16*)alloc((size_t)N * INNERC * 2);
    __hip_bfloat16* u      = (__hip_bfloat16*)alloc((size_t)N * 1024 * 2);
    int*            rowptr = (int*)alloc((size_t)(N + 1) * 4);
    int*            cnt    = (int*)alloc((size_t)N * 4);
    int*            srcperm= (int*)alloc((size_t)E * 4);
    __hip_bfloat16* wqkvB  = (__hip_bfloat16*)alloc((size_t)4 * QKVC * DIMC * 2);
    float*          bqkvF  = (float*)alloc((size_t)4 * QKVC * 4);
    __hip_bfloat16* woB    = (__hip_bfloat16*)alloc((size_t)4 * DIMC * INNERC * 2);
    __hip_bfloat16* w1B    = (__hip_bfloat16*)alloc((size_t)4 * 1024 * DIMC * 2);
    __hip_bfloat16* w2B    = (__hip_bfloat16*)alloc((size_t)4 * DIMC * 1024 * 2);

    // Weight conversion (per-call, deterministic)
    packqkv_kernel<<<4 * QKVC, 256, 0, stream>>>(wq, wk, wv, bq, bk, bv, wqkvB, bqkvF);
    {
        int n = 4 * DIMC * INNERC;
        f2b_kernel<<<(n / 4 + 255) / 256, 256, 0, stream>>>(wo, woB, n);
        n = 4 * 1024 * DIMC;
        f2b_kernel<<<(n / 4 + 255) / 256, 256, 0, stream>>>(w1, w1B, n);
        f2b_kernel<<<(n / 4 + 255) / 256, 256, 0, stream>>>(w2, w2B, n);
    }

    // CSR build
    hipMemsetAsync(cnt, 0, (size_t)N * 4, stream);
    count_kernel<<<(E + 255) / 256, 256, 0, stream>>>(dstIdx, cnt, E);
    scan_kernel<<<1, 1024, 0, stream>>>(cnt, rowptr, N);
    hipMemsetAsync(cnt, 0, (size_t)N * 4, stream);
    scatter_kernel<<<(E + 255) / 256, 256, 0, stream>>>(srcIdx, dstIdx, rowptr, cnt, srcperm, E);

    int mt = (N + 127) / 128;   // 157
    int attnBlocks = (N * 64 + 255) / 256;   // one wave per node
    for (int l = 0; l < 4; ++l) {
        const float* xin = (l == 0) ? x : xbuf;
        ln_kernel<<<N, 256, 0, stream>>>(xin, ln1g + l * DIMC, ln1b + l * DIMC, h);
        mfma_gemm<0><<<dim3(mt, QKVC / 128), 256, 0, stream>>>(
            h, wqkvB + (size_t)l * QKVC * DIMC, bqkvF + l * QKVC, nullptr,
            qkv, N, DIMC, QKVC);
        attn_kernel<<<attnBlocks, 256, 0, stream>>>(qkv, rowptr, srcperm, agg, N);
        mfma_gemm<2><<<dim3(mt, DIMC / 128), 256, 0, stream>>>(
            agg, woB + (size_t)l * DIMC * INNERC, bo + l * DIMC, xin,
            xbuf, N, INNERC, DIMC);
        ln_kernel<<<N, 256, 0, stream>>>(xbuf, ln2g + l * DIMC, ln2b + l * DIMC, h);
        mfma_gemm<1><<<dim3(mt, 1024 / 128), 256, 0, stream>>>(
            h, w1B + (size_t)l * 1024 * DIMC, b1 + l * 1024, nullptr,
            u, N, DIMC, 1024);
        float* xout = (l == 3) ? (float*)d_out : xbuf;
        mfma_gemm<2><<<dim3(mt, DIMC / 128), 256, 0, stream>>>(
            u, w2B + (size_t)l * DIMC * 1024, b2 + l * DIMC, xbuf,
            xout, N, 1024, DIMC);
    }
}